// Round 1
// baseline (1880.080 us; speedup 1.0000x reference)
//
#include <hip/hip_runtime.h>
#include <hip/hip_bf16.h>

// QuantizedMoEExpert: out[8192,14336] = x[8192,4096] @ dequant(packed)[14336,4096]^T
// Round 1: fused dequant + bf16 MFMA GEMM (16x16x32), 128x128 tile, BK=64.
// Dequant happens in the LDS staging path (VALU); expect VALU-bound ~300-400 TF.

typedef __bf16 bf16x8 __attribute__((ext_vector_type(8)));
typedef __bf16 bf16x4 __attribute__((ext_vector_type(4)));
typedef float floatx4 __attribute__((ext_vector_type(4)));

#define M_DIM 8192
#define K_DIM 4096
#define N_DIM 14336
#define KB    (K_DIM / 2)   // packed int32 elements per output row (each holds 2 nibbles)

#define BM 128
#define BN 128
#define BK 64
#define LDSK 72             // padded LDS row stride (bf16 elems): 144 B -> <=2-way bank aliasing

__global__ __launch_bounds__(256) void qgemm_bf16(
    const float* __restrict__ X,   // [M, K] fp32
    const int*   __restrict__ P,   // [N, K/2] packed int4 pairs (one byte value per int32)
    const float* __restrict__ S,   // [N] scales
    const float* __restrict__ Z,   // [N] zero points
    float*       __restrict__ O)   // [M, N]
{
    __shared__ __bf16 Alds[BM * LDSK];
    __shared__ __bf16 Blds[BN * LDSK];

    const int t  = threadIdx.x;
    const int bn = blockIdx.x;     // N tile
    const int bm = blockIdx.y;     // M tile

    // ---- staging maps ----
    // A: 128 rows x 64 fp32 cols = 2048 float4 / 256 threads = 8 each.
    //    linear idx = t + 256*it -> row = idx>>4 = (t>>4) + 16*it, chunk c4 = t&15
    const int rowA0 = t >> 4;
    const int c4    = t & 15;
    // B: 128 rows x 32 int32 = 4096 / 256 threads = 16 int32 = 4 int4 each.
    //    idx = t + 256*it -> row = (t>>3) + 32*it, chunk cB = t&7
    const int rowB0 = t >> 3;
    const int cB    = t & 7;

    const float* aG = X + (size_t)(bm * BM + rowA0) * K_DIM + c4 * 4;
    const int*   bG = P + (size_t)(bn * BN + rowB0) * KB    + cB * 4;

    // per-thread row constants for dequant (row fixed across K loop)
    float sreg[4], oreg[4];
    for (int it = 0; it < 4; ++it) {
        int r = bn * BN + rowB0 + 32 * it;
        float s = S[r], z = Z[r];
        sreg[it] = s;
        oreg[it] = -z * s;          // w = v*s + (-z*s)
    }

    // ---- compute maps ----
    const int lane = t & 63;
    const int wave = t >> 6;        // 4 waves: 2x2 grid of 64x64 sub-tiles
    const int wm   = wave >> 1;
    const int wn   = wave & 1;
    const int fr   = lane & 15;     // fragment row (A) / col (B) / output col
    const int quad = lane >> 4;

    floatx4 acc[4][4];
    for (int i = 0; i < 4; ++i)
        for (int j = 0; j < 4; ++j)
            acc[i][j] = (floatx4)0.0f;

    const __bf16* aBase = &Alds[(wm * 64 + fr) * LDSK + quad * 8];
    const __bf16* bBase = &Blds[(wn * 64 + fr) * LDSK + quad * 8];

    for (int kt = 0; kt < K_DIM / BK; ++kt) {
        // ---- global loads (batched so vmcnt overlaps) ----
        float4 av[8];
        for (int it = 0; it < 8; ++it)
            av[it] = *(const float4*)(aG + (size_t)it * 16 * K_DIM);
        int4 bv[4];
        for (int it = 0; it < 4; ++it)
            bv[it] = *(const int4*)(bG + (size_t)it * 32 * KB);
        aG += BK;
        bG += BK / 2;

        // ---- stage A: fp32 -> bf16 ----
        for (int it = 0; it < 8; ++it) {
            bf16x4 w;
            w[0] = (__bf16)av[it].x;
            w[1] = (__bf16)av[it].y;
            w[2] = (__bf16)av[it].z;
            w[3] = (__bf16)av[it].w;
            *(bf16x4*)&Alds[(rowA0 + 16 * it) * LDSK + c4 * 4] = w;
        }
        // ---- stage B: unpack nibbles, dequant, -> bf16 ----
        for (int it = 0; it < 4; ++it) {
            const float s = sreg[it], o = oreg[it];
            const int b0 = bv[it].x, b1 = bv[it].y, b2 = bv[it].z, b3 = bv[it].w;
            bf16x8 w;
            w[0] = (__bf16)((float)(b0 & 15) * s + o);
            w[1] = (__bf16)((float)((b0 >> 4) & 15) * s + o);
            w[2] = (__bf16)((float)(b1 & 15) * s + o);
            w[3] = (__bf16)((float)((b1 >> 4) & 15) * s + o);
            w[4] = (__bf16)((float)(b2 & 15) * s + o);
            w[5] = (__bf16)((float)((b2 >> 4) & 15) * s + o);
            w[6] = (__bf16)((float)(b3 & 15) * s + o);
            w[7] = (__bf16)((float)((b3 >> 4) & 15) * s + o);
            *(bf16x8*)&Blds[(rowB0 + 32 * it) * LDSK + cB * 8] = w;
        }
        __syncthreads();

        // ---- MFMA inner loop: 2 k-steps of 32, 4x4 tiles of 16x16 per wave ----
        for (int kk = 0; kk < BK; kk += 32) {
            bf16x8 af[4], bf[4];
            for (int i = 0; i < 4; ++i)
                af[i] = *(const bf16x8*)(aBase + (i * 16) * LDSK + kk);
            for (int j = 0; j < 4; ++j)
                bf[j] = *(const bf16x8*)(bBase + (j * 16) * LDSK + kk);
            for (int i = 0; i < 4; ++i)
                for (int j = 0; j < 4; ++j)
                    acc[i][j] = __builtin_amdgcn_mfma_f32_16x16x32_bf16(
                        af[i], bf[j], acc[i][j], 0, 0, 0);
        }
        __syncthreads();
    }

    // ---- epilogue: C/D layout col=lane&15, row=quad*4+reg ----
    for (int i = 0; i < 4; ++i) {
        const int row = bm * BM + wm * 64 + i * 16 + quad * 4;
        for (int j = 0; j < 4; ++j) {
            const int col = bn * BN + wn * 64 + j * 16 + fr;
            float* o = O + (size_t)row * N_DIM + col;
            for (int r = 0; r < 4; ++r)
                o[(size_t)r * N_DIM] = acc[i][j][r];
        }
    }
}

extern "C" void kernel_launch(void* const* d_in, const int* in_sizes, int n_in,
                              void* d_out, int out_size, void* d_ws, size_t ws_size,
                              hipStream_t stream) {
    const float* x = (const float*)d_in[0];
    const int*   p = (const int*)d_in[1];
    const float* s = (const float*)d_in[2];
    const float* z = (const float*)d_in[3];
    float* out = (float*)d_out;

    dim3 grid(N_DIM / BN, M_DIM / BM);   // 112 x 64 = 7168 blocks
    qgemm_bf16<<<grid, 256, 0, stream>>>(x, p, s, z, out);
}